// Round 4
// baseline (436.521 us; speedup 1.0000x reference)
//
#include <hip/hip_runtime.h>

// Problem constants (fixed by reference)
#define DB 8
#define DT 4096
#define DC 1024
#define GM (DB*DT)   // 32768
#define GN (2*DC)    // 2048 (state cols 0..1023, gate cols 1024..2047)
#define GK DC        // 1024

// Segmented-scan parameters
#define SEG 64       // segment length (outputs per worker)
#define NSEG (DT/SEG)
#define WU 64        // warmup steps (contraction ~0.55/step kills s0 error)
#define UCH 8        // prefetch chunk depth
#define VEC 4        // channels per thread (f16x4 loads, f32x4 stores)

typedef _Float16 f16;
typedef _Float16 f16x8 __attribute__((ext_vector_type(8)));
typedef _Float16 f16x4 __attribute__((ext_vector_type(4)));
typedef float    f32x4 __attribute__((ext_vector_type(4)));

__device__ __forceinline__ void async_copy16(const void* g, void* l) {
    __builtin_amdgcn_global_load_lds((const __attribute__((address_space(1))) void*)g,
                                     (__attribute__((address_space(3))) void*)l,
                                     16, 0, 0);
}

// ---- fp32 -> f16 conversion of x -------------------------------------------
__global__ __launch_bounds__(256) void conv_x_kernel(const float* __restrict__ x,
                                                     f16* __restrict__ xh) {
    const size_t i = (size_t)blockIdx.x * 256 + threadIdx.x;
    const f32x4 v = *(const f32x4*)(x + 4*i);
    f16x4 h; h.x = (f16)v.x; h.y = (f16)v.y; h.z = (f16)v.z; h.w = (f16)v.w;
    *(f16x4*)(xh + 4*i) = h;
}

// ---- fp32 -> f16 of [W_state; W_gate] as one [2048,1024] row-major matrix --
__global__ __launch_bounds__(256) void conv_w_kernel(const float* __restrict__ Ws,
                                                     const float* __restrict__ Wg,
                                                     f16* __restrict__ wc) {
    const int i = blockIdx.x * 256 + threadIdx.x;
    const int e = i * 4;
    const int n = e >> 10;
    const int k = e & 1023;
    const float* src = (n < DC) ? (Ws + (size_t)n * DC + k)
                                : (Wg + (size_t)(n - DC) * DC + k);
    const f32x4 v = *(const f32x4*)src;
    f16x4 h; h.x = (f16)v.x; h.y = (f16)v.y; h.z = (f16)v.z; h.w = (f16)v.w;
    *(f16x4*)(wc + e) = h;
}

// ---- fused GEMM: [32768,1024] x [2048,1024]^T, bias + (sigmoid for gate) ---
// ROUND-0 PROVEN VERSION (171 us, MfmaUtil 38%). Two 8-phase 256^2 ports both
// regressed (195/201 us, MfmaUtil ~30%) -- the lockstep double-barrier phases
// serialize ds_read vs MFMA at 2 waves/SIMD; parked until asm-level evidence.
// 128x128 tile, BK=64, 4 waves, each 64x64 via 4x4 grid of 16x16x32 f16 MFMAs.
// LDS uses an XOR-8 chunk swizzle: logical (row, chunk c) lives at physical
// chunk c^(row&7). Staging picks the swizzled GLOBAL source per lane (the
// lane->LDS mapping of global_load_lds is fixed); fragment reads XOR on the
// LDS side. Result: each ds_read_b128 spreads over all 32 banks.
__global__ __launch_bounds__(256, 4) void gemm_kernel(
        const f16* __restrict__ xh, const f16* __restrict__ wc,
        const float* __restrict__ b_state, const float* __restrict__ b_gate,
        f16* __restrict__ pxh, f16* __restrict__ gh) {
    __shared__ f16 lds_a[128 * 64];
    __shared__ f16 lds_b[128 * 64];

    const int tid  = threadIdx.x;
    const int lane = tid & 63;
    // XCD-aware remap: blocks land on XCD (blockIdx.x & 7) [heuristic].
    // Give each XCD a 32-row slab of bm with bn fastest: B (4 MB) stays
    // resident in that XCD's L2; each A tile is read by exactly one XCD.
    const int xcd = blockIdx.x & 7;
    const int lin = blockIdx.x >> 3;       // 0..511
    const int bm  = xcd * 32 + (lin >> 4); // 0..255
    const int bn  = lin & 15;              // 0..15
    const int wave = tid >> 6;
    const int wm   = (wave & 1) * 64;
    const int wn   = (wave >> 1) * 64;
    const int lr   = lane & 15;
    const int lq   = lane >> 4;

    f32x4 acc[4][4] = {};

    const int kc = tid & 7;                // dest 16B chunk within 64-half row
    const int rw = tid >> 3;               // dest row (within 32-row stripe)
    const int kg = kc ^ (rw & 7);          // swizzled global source chunk
    const int ldsbase = (tid & 192) * 16;  // wave-uniform byte base
    const int sw = lr & 7;                 // read-side swizzle key (row&7)

    for (int kt = 0; kt < GK / 64; ++kt) {
        const int k0 = kt * 64;
        #pragma unroll
        for (int i = 0; i < 4; ++i) {
            const int row = i * 32 + rw;
            async_copy16(xh + (size_t)(bm * 128 + row) * GK + k0 + kg * 8,
                         (char*)lds_a + ldsbase + i * 4096);
            async_copy16(wc + (size_t)(bn * 128 + row) * GK + k0 + kg * 8,
                         (char*)lds_b + ldsbase + i * 4096);
        }
        __syncthreads();
        #pragma unroll
        for (int ks = 0; ks < 2; ++ks) {
            f16x8 af[4], bf[4];
            #pragma unroll
            for (int t = 0; t < 4; ++t) {
                const int pc = (ks * 4 + lq) ^ sw;   // physical chunk
                af[t] = *(const f16x8*)&lds_a[(wm + t * 16 + lr) * 64 + pc * 8];
                bf[t] = *(const f16x8*)&lds_b[(wn + t * 16 + lr) * 64 + pc * 8];
            }
            #pragma unroll
            for (int im = 0; im < 4; ++im)
                #pragma unroll
                for (int in = 0; in < 4; ++in)
                    acc[im][in] = __builtin_amdgcn_mfma_f32_16x16x32_f16(
                        af[im], bf[in], acc[im][in], 0, 0, 0);
        }
        __syncthreads();
    }

    // Epilogue. D layout: col = lane&15, row = quad*4 + reg (verified m89).
    const int gm0 = bm * 128 + wm + lq * 4;
    const int gn0 = bn * 128 + wn + lr;
    if (bn < 8) {
        #pragma unroll
        for (int in = 0; in < 4; ++in) {
            const int gn = gn0 + in * 16;
            const float bias = b_state[gn];
            #pragma unroll
            for (int im = 0; im < 4; ++im) {
                const int gm = gm0 + im * 16;
                #pragma unroll
                for (int r = 0; r < 4; ++r)
                    pxh[(size_t)(gm + r) * DC + gn] = (f16)(acc[im][in][r] + bias);
            }
        }
    } else {
        #pragma unroll
        for (int in = 0; in < 4; ++in) {
            const int gn   = gn0 + in * 16;
            const int gcol = gn - DC;
            const float bias = b_gate[gcol];
            #pragma unroll
            for (int im = 0; im < 4; ++im) {
                const int gm = gm0 + im * 16;
                #pragma unroll
                for (int r = 0; r < 4; ++r) {
                    const float v = acc[im][in][r] + bias;
                    gh[(size_t)(gm + r) * DC + gcol] = (f16)(1.0f / (1.0f + __expf(-v)));
                }
            }
        }
    }
}

// ---- segmented scan over T: s = tanh(p_t + s); out = g_t * s ---------------
// VECTORIZED across channels (G13): each thread owns VEC=4 adjacent channels
// of one (b, seg) -> f16x4 loads (8 B/lane vs scalar 2 B/lane before) and
// f32x4 stores (16 B/lane). 4 independent recurrence chains per thread give
// ILP on the fma->exp2->add->rcp->fma dependent path. 2048 groups x 64 segs
// = 131072 threads = 8 waves/CU, pure streaming; ~90 VGPR, no spill.
// Numerics identical per channel to the scalar version (same segmentation,
// same warmup), so absmax is unchanged.
// tanh(z) = 1 - 2/(1+2^(L*z)), L = 2*log2(e); track sL = L*s.
__global__ __launch_bounds__(256) void scan_kernel(
        const f16* __restrict__ ph, const f16* __restrict__ gh,
        float* __restrict__ out) {
    const int tau = blockIdx.x * 256 + threadIdx.x;     // 0..131071
    const int seg = tau >> 11;                          // 0..63 (block-uniform)
    const int grp = tau & 2047;                         // channel group
    const int b   = grp >> 8;                           // 0..7
    const int c0  = (grp & 255) * VEC;                  // 0..1020
    const size_t base = (size_t)b * ((size_t)DT * DC) + c0;
    const float L = 2.8853900817779268f;                // 2*log2(e)
    float sL[VEC], sv[VEC];
    #pragma unroll
    for (int v = 0; v < VEC; ++v) { sL[v] = 0.0f; sv[v] = 0.0f; }
    const int t0 = seg * SEG;

    if (seg) {  // warmup: p only, no g, no stores
        const int tw = t0 - WU;
        f16x4 wA[UCH], wB[UCH];
        #pragma unroll
        for (int i = 0; i < UCH; ++i)
            wA[i] = *(const f16x4*)&ph[base + (size_t)(tw + i) * DC];
        #pragma unroll 1
        for (int ch = 0; ch < WU / UCH; ++ch) {
            #pragma unroll
            for (int i = 0; i < UCH; ++i)   // last iter reads t0..t0+7: valid
                wB[i] = *(const f16x4*)&ph[base + (size_t)(tw + (ch + 1) * UCH + i) * DC];
            #pragma unroll
            for (int i = 0; i < UCH; ++i)
                #pragma unroll
                for (int v = 0; v < VEC; ++v) {
                    const float u = fmaf((float)wA[i][v], L, sL[v]);
                    const float e = __builtin_amdgcn_exp2f(u);
                    const float r = __builtin_amdgcn_rcpf(e + 1.0f);
                    sL[v] = fmaf(-2.0f * L, r, L);
                }
            #pragma unroll
            for (int i = 0; i < UCH; ++i) wA[i] = wB[i];
        }
    }

    f16x4 pA[UCH], pB[UCH], gA[UCH], gB[UCH];
    #pragma unroll
    for (int i = 0; i < UCH; ++i) {
        const size_t idx = base + (size_t)(t0 + i) * DC;
        pA[i] = *(const f16x4*)&ph[idx];
        gA[i] = *(const f16x4*)&gh[idx];
    }
    #pragma unroll 1
    for (int ch = 0; ch < SEG / UCH; ++ch) {
        // Unconditional next-chunk prefetch (ph/gh padded by 16 rows, so
        // segment 63's final prefetch at t=4096..4103 stays in bounds).
        #pragma unroll
        for (int i = 0; i < UCH; ++i) {
            const size_t idx = base + (size_t)(t0 + (ch + 1) * UCH + i) * DC;
            pB[i] = *(const f16x4*)&ph[idx];
            gB[i] = *(const f16x4*)&gh[idx];
        }
        #pragma unroll
        for (int i = 0; i < UCH; ++i) {
            f32x4 o;
            #pragma unroll
            for (int v = 0; v < VEC; ++v) {
                const float u = fmaf((float)pA[i][v], L, sL[v]);
                const float e = __builtin_amdgcn_exp2f(u);
                const float r = __builtin_amdgcn_rcpf(e + 1.0f);
                sv[v] = fmaf(-2.0f, r, 1.0f);
                sL[v] = fmaf(-2.0f * L, r, L);
                o[v]  = (float)gA[i][v] * sv[v];
            }
            *(f32x4*)&out[base + (size_t)(t0 + ch * UCH + i) * DC] = o;
        }
        #pragma unroll
        for (int i = 0; i < UCH; ++i) { pA[i] = pB[i]; gA[i] = gB[i]; }
    }
    if (seg == NSEG - 1) {  // final_state [B,C] appended after outs
        f32x4 fs;
        #pragma unroll
        for (int v = 0; v < VEC; ++v) fs[v] = sv[v];
        *(f32x4*)&out[(size_t)DB * DT * DC + b * DC + c0] = fs;
    }
}

extern "C" void kernel_launch(void* const* d_in, const int* in_sizes, int n_in,
                              void* d_out, int out_size, void* d_ws, size_t ws_size,
                              hipStream_t stream) {
    const float* x  = (const float*)d_in[0];
    const float* Ws = (const float*)d_in[1];
    const float* bs = (const float*)d_in[2];
    const float* Wg = (const float*)d_in[3];
    const float* bg = (const float*)d_in[4];
    float* out = (float*)d_out;

    // workspace layout (~196 MiB):
    //   xh  f16[32768][1024], wc f16[2048][1024],
    //   pxh f16[32768+16][1024], gh f16[32768+16][1024]
    char* ws = (char*)d_ws;
    const size_t SZ_XH  = (size_t)GM * GK * 2;
    const size_t SZ_WC  = (size_t)GN * GK * 2;
    const size_t SZ_PXH = ((size_t)GM + 16) * DC * 2;
    f16* xh  = (f16*)ws;
    f16* wc  = (f16*)(ws + SZ_XH);
    f16* pxh = (f16*)(ws + SZ_XH + SZ_WC);
    f16* gh  = (f16*)(ws + SZ_XH + SZ_WC + SZ_PXH);

    conv_x_kernel<<<dim3(GM * GK / 1024), dim3(256), 0, stream>>>(x, xh);
    conv_w_kernel<<<dim3(GN * GK / 1024), dim3(256), 0, stream>>>(Ws, Wg, wc);
    gemm_kernel<<<dim3(4096), dim3(256), 0, stream>>>(xh, wc, bs, bg, pxh, gh);
    scan_kernel<<<dim3(DB * DC * NSEG / VEC / 256), dim3(256), 0, stream>>>(pxh, gh, out);
}

// Round 5
// 425.527 us; speedup vs baseline: 1.0258x; 1.0258x over previous
//
#include <hip/hip_runtime.h>

// Problem constants (fixed by reference)
#define DB 8
#define DT 4096
#define DC 1024
#define GM (DB*DT)   // 32768
#define GN (2*DC)    // 2048 (state cols 0..1023, gate cols 1024..2047)
#define GK DC        // 1024

// Segmented-scan parameters
#define SEG 64       // segment length (outputs per worker)
#define NSEG (DT/SEG)
#define WU 64        // warmup steps (contraction ~0.55/step kills s0 error)
#define UCH 16       // prefetch chunk depth (128 B/thread in flight)
#define VEC 2        // channels per thread (f16x2 loads, f32x2 stores)

typedef _Float16 f16;
typedef _Float16 f16x8 __attribute__((ext_vector_type(8)));
typedef _Float16 f16x4 __attribute__((ext_vector_type(4)));
typedef _Float16 f16x2 __attribute__((ext_vector_type(2)));
typedef float    f32x4 __attribute__((ext_vector_type(4)));
typedef float    f32x2 __attribute__((ext_vector_type(2)));

__device__ __forceinline__ void async_copy16(const void* g, void* l) {
    __builtin_amdgcn_global_load_lds((const __attribute__((address_space(1))) void*)g,
                                     (__attribute__((address_space(3))) void*)l,
                                     16, 0, 0);
}

// ---- fp32 -> f16 conversion of x -------------------------------------------
__global__ __launch_bounds__(256) void conv_x_kernel(const float* __restrict__ x,
                                                     f16* __restrict__ xh) {
    const size_t i = (size_t)blockIdx.x * 256 + threadIdx.x;
    const f32x4 v = *(const f32x4*)(x + 4*i);
    f16x4 h; h.x = (f16)v.x; h.y = (f16)v.y; h.z = (f16)v.z; h.w = (f16)v.w;
    *(f16x4*)(xh + 4*i) = h;
}

// ---- fp32 -> f16 of [W_state; W_gate] as one [2048,1024] row-major matrix --
__global__ __launch_bounds__(256) void conv_w_kernel(const float* __restrict__ Ws,
                                                     const float* __restrict__ Wg,
                                                     f16* __restrict__ wc) {
    const int i = blockIdx.x * 256 + threadIdx.x;
    const int e = i * 4;
    const int n = e >> 10;
    const int k = e & 1023;
    const float* src = (n < DC) ? (Ws + (size_t)n * DC + k)
                                : (Wg + (size_t)(n - DC) * DC + k);
    const f32x4 v = *(const f32x4*)src;
    f16x4 h; h.x = (f16)v.x; h.y = (f16)v.y; h.z = (f16)v.z; h.w = (f16)v.w;
    *(f16x4*)(wc + e) = h;
}

// ---- fused GEMM: [32768,1024] x [2048,1024]^T, bias + (sigmoid for gate) ---
// FROZEN CONTROL (R4: 155.8 us, MfmaUtil 41.6%, 881 TF = m97-structure
// ceiling). Two 8-phase 256^2 ports both regressed (195/201 us); parked.
// 128x128 tile, BK=64, 4 waves, each 64x64 via 4x4 grid of 16x16x32 f16 MFMAs.
// LDS uses an XOR-8 chunk swizzle: logical (row, chunk c) lives at physical
// chunk c^(row&7). Staging picks the swizzled GLOBAL source per lane (the
// lane->LDS mapping of global_load_lds is fixed); fragment reads XOR on the
// LDS side. Result: each ds_read_b128 spreads over all 32 banks.
__global__ __launch_bounds__(256, 4) void gemm_kernel(
        const f16* __restrict__ xh, const f16* __restrict__ wc,
        const float* __restrict__ b_state, const float* __restrict__ b_gate,
        f16* __restrict__ pxh, f16* __restrict__ gh) {
    __shared__ f16 lds_a[128 * 64];
    __shared__ f16 lds_b[128 * 64];

    const int tid  = threadIdx.x;
    const int lane = tid & 63;
    // XCD-aware remap: blocks land on XCD (blockIdx.x & 7) [heuristic].
    const int xcd = blockIdx.x & 7;
    const int lin = blockIdx.x >> 3;       // 0..511
    const int bm  = xcd * 32 + (lin >> 4); // 0..255
    const int bn  = lin & 15;              // 0..15
    const int wave = tid >> 6;
    const int wm   = (wave & 1) * 64;
    const int wn   = (wave >> 1) * 64;
    const int lr   = lane & 15;
    const int lq   = lane >> 4;

    f32x4 acc[4][4] = {};

    const int kc = tid & 7;                // dest 16B chunk within 64-half row
    const int rw = tid >> 3;               // dest row (within 32-row stripe)
    const int kg = kc ^ (rw & 7);          // swizzled global source chunk
    const int ldsbase = (tid & 192) * 16;  // wave-uniform byte base
    const int sw = lr & 7;                 // read-side swizzle key (row&7)

    for (int kt = 0; kt < GK / 64; ++kt) {
        const int k0 = kt * 64;
        #pragma unroll
        for (int i = 0; i < 4; ++i) {
            const int row = i * 32 + rw;
            async_copy16(xh + (size_t)(bm * 128 + row) * GK + k0 + kg * 8,
                         (char*)lds_a + ldsbase + i * 4096);
            async_copy16(wc + (size_t)(bn * 128 + row) * GK + k0 + kg * 8,
                         (char*)lds_b + ldsbase + i * 4096);
        }
        __syncthreads();
        #pragma unroll
        for (int ks = 0; ks < 2; ++ks) {
            f16x8 af[4], bf[4];
            #pragma unroll
            for (int t = 0; t < 4; ++t) {
                const int pc = (ks * 4 + lq) ^ sw;   // physical chunk
                af[t] = *(const f16x8*)&lds_a[(wm + t * 16 + lr) * 64 + pc * 8];
                bf[t] = *(const f16x8*)&lds_b[(wn + t * 16 + lr) * 64 + pc * 8];
            }
            #pragma unroll
            for (int im = 0; im < 4; ++im)
                #pragma unroll
                for (int in = 0; in < 4; ++in)
                    acc[im][in] = __builtin_amdgcn_mfma_f32_16x16x32_f16(
                        af[im], bf[in], acc[im][in], 0, 0, 0);
        }
        __syncthreads();
    }

    // Epilogue. D layout: col = lane&15, row = quad*4 + reg (verified m89).
    const int gm0 = bm * 128 + wm + lq * 4;
    const int gn0 = bn * 128 + wn + lr;
    if (bn < 8) {
        #pragma unroll
        for (int in = 0; in < 4; ++in) {
            const int gn = gn0 + in * 16;
            const float bias = b_state[gn];
            #pragma unroll
            for (int im = 0; im < 4; ++im) {
                const int gm = gm0 + im * 16;
                #pragma unroll
                for (int r = 0; r < 4; ++r)
                    pxh[(size_t)(gm + r) * DC + gn] = (f16)(acc[im][in][r] + bias);
            }
        }
    } else {
        #pragma unroll
        for (int in = 0; in < 4; ++in) {
            const int gn   = gn0 + in * 16;
            const int gcol = gn - DC;
            const float bias = b_gate[gcol];
            #pragma unroll
            for (int im = 0; im < 4; ++im) {
                const int gm = gm0 + im * 16;
                #pragma unroll
                for (int r = 0; r < 4; ++r) {
                    const float v = acc[im][in][r] + bias;
                    gh[(size_t)(gm + r) * DC + gcol] = (f16)(1.0f / (1.0f + __expf(-v)));
                }
            }
        }
    }
}

// ---- segmented scan over T: s = tanh(p_t + s); out = g_t * s ---------------
// R5 theory: scan is latency/TLP-bound (~150 us vs 51 us traffic floor).
// VEC=2 + SEG=64 -> 262144 workers = 16 waves/CU (2x R4's TLP), f16x2 loads
// (4 B/lane, 256 B/wave contiguous), 2 independent chains/thread for ILP on
// the fma->exp2->add->rcp->fma dependent path. UCH=16 deepens prefetch to
// 128 B/thread in flight (128 KB/CU >> Little's-law need at ~900 cyc).
// Non-temporal stores: out (128 MB) is write-once, keep it out of L2.
// Numerics bit-identical per channel to all prior rounds (same segmentation,
// same WU=64 warmup) -> absmax unchanged.
// tanh(z) = 1 - 2/(1+2^(L*z)), L = 2*log2(e); track sL = L*s.
__global__ __launch_bounds__(256, 4) void scan_kernel(
        const f16* __restrict__ ph, const f16* __restrict__ gh,
        float* __restrict__ out) {
    const int tau = blockIdx.x * 256 + threadIdx.x;     // 0..262143
    const int seg = tau >> 12;                          // 0..63 (wave-uniform)
    const int grp = tau & 4095;                         // channel-pair group
    const int b   = grp >> 9;                           // 0..7
    const int c0  = (grp & 511) * VEC;                  // 0..1022 (even)
    const size_t base = (size_t)b * ((size_t)DT * DC) + c0;
    const float L = 2.8853900817779268f;                // 2*log2(e)
    float sL[VEC], sv[VEC];
    #pragma unroll
    for (int v = 0; v < VEC; ++v) { sL[v] = 0.0f; sv[v] = 0.0f; }
    const int t0 = seg * SEG;

    if (seg) {  // warmup: p only, no g, no stores
        const int tw = t0 - WU;
        f16x2 wA[UCH], wB[UCH];
        #pragma unroll
        for (int i = 0; i < UCH; ++i)
            wA[i] = *(const f16x2*)&ph[base + (size_t)(tw + i) * DC];
        #pragma unroll 1
        for (int ch = 0; ch < WU / UCH; ++ch) {
            #pragma unroll
            for (int i = 0; i < UCH; ++i)   // last iter reads t0..t0+15: valid
                wB[i] = *(const f16x2*)&ph[base + (size_t)(tw + (ch + 1) * UCH + i) * DC];
            #pragma unroll
            for (int i = 0; i < UCH; ++i)
                #pragma unroll
                for (int v = 0; v < VEC; ++v) {
                    const float u = fmaf((float)wA[i][v], L, sL[v]);
                    const float e = __builtin_amdgcn_exp2f(u);
                    const float r = __builtin_amdgcn_rcpf(e + 1.0f);
                    sL[v] = fmaf(-2.0f * L, r, L);
                }
            #pragma unroll
            for (int i = 0; i < UCH; ++i) wA[i] = wB[i];
        }
    }

    f16x2 pA[UCH], pB[UCH], gA[UCH], gB[UCH];
    #pragma unroll
    for (int i = 0; i < UCH; ++i) {
        const size_t idx = base + (size_t)(t0 + i) * DC;
        pA[i] = *(const f16x2*)&ph[idx];
        gA[i] = *(const f16x2*)&gh[idx];
    }
    #pragma unroll 1
    for (int ch = 0; ch < SEG / UCH; ++ch) {
        // Unconditional next-chunk prefetch (ph/gh padded by 16 rows, so
        // segment 63's final prefetch at t=4096..4111 stays in bounds).
        #pragma unroll
        for (int i = 0; i < UCH; ++i) {
            const size_t idx = base + (size_t)(t0 + (ch + 1) * UCH + i) * DC;
            pB[i] = *(const f16x2*)&ph[idx];
            gB[i] = *(const f16x2*)&gh[idx];
        }
        #pragma unroll
        for (int i = 0; i < UCH; ++i) {
            f32x2 o;
            #pragma unroll
            for (int v = 0; v < VEC; ++v) {
                const float u = fmaf((float)pA[i][v], L, sL[v]);
                const float e = __builtin_amdgcn_exp2f(u);
                const float r = __builtin_amdgcn_rcpf(e + 1.0f);
                sv[v] = fmaf(-2.0f, r, 1.0f);
                sL[v] = fmaf(-2.0f * L, r, L);
                o[v]  = (float)gA[i][v] * sv[v];
            }
            __builtin_nontemporal_store(o,
                (f32x2*)&out[base + (size_t)(t0 + ch * UCH + i) * DC]);
        }
        #pragma unroll
        for (int i = 0; i < UCH; ++i) { pA[i] = pB[i]; gA[i] = gB[i]; }
    }
    if (seg == NSEG - 1) {  // final_state [B,C] appended after outs
        f32x2 fs;
        #pragma unroll
        for (int v = 0; v < VEC; ++v) fs[v] = sv[v];
        *(f32x2*)&out[(size_t)DB * DT * DC + b * DC + c0] = fs;
    }
}

extern "C" void kernel_launch(void* const* d_in, const int* in_sizes, int n_in,
                              void* d_out, int out_size, void* d_ws, size_t ws_size,
                              hipStream_t stream) {
    const float* x  = (const float*)d_in[0];
    const float* Ws = (const float*)d_in[1];
    const float* bs = (const float*)d_in[2];
    const float* Wg = (const float*)d_in[3];
    const float* bg = (const float*)d_in[4];
    float* out = (float*)d_out;

    // workspace layout (~196 MiB):
    //   xh  f16[32768][1024], wc f16[2048][1024],
    //   pxh f16[32768+16][1024], gh f16[32768+16][1024]
    char* ws = (char*)d_ws;
    const size_t SZ_XH  = (size_t)GM * GK * 2;
    const size_t SZ_WC  = (size_t)GN * GK * 2;
    const size_t SZ_PXH = ((size_t)GM + 16) * DC * 2;
    f16* xh  = (f16*)ws;
    f16* wc  = (f16*)(ws + SZ_XH);
    f16* pxh = (f16*)(ws + SZ_XH + SZ_WC);
    f16* gh  = (f16*)(ws + SZ_XH + SZ_WC + SZ_PXH);

    conv_x_kernel<<<dim3(GM * GK / 1024), dim3(256), 0, stream>>>(x, xh);
    conv_w_kernel<<<dim3(GN * GK / 1024), dim3(256), 0, stream>>>(Ws, Wg, wc);
    gemm_kernel<<<dim3(4096), dim3(256), 0, stream>>>(xh, wc, bs, bg, pxh, gh);
    scan_kernel<<<dim3(DB * DC * NSEG / VEC / 256), dim3(256), 0, stream>>>(pxh, gh, out);
}